// Round 1
// baseline (399.592 us; speedup 1.0000x reference)
//
#include <hip/hip_runtime.h>
#include <cstdint>
#include <cstddef>

#define N_ 2
#define B_ 2
#define D_ 512
#define HW_ 256
#define DK_ 64
#define DKC_ 128
#define G_ 4
#define NBLK_ 32

// ---- workspace offsets (in floats) ----
constexpr size_t OFF_TSR = 0;                       // src_real tokens [(n*hw), b, d]
constexpr size_t OFF_TSI = 524288;
constexpr size_t OFF_TTR = 1048576;
constexpr size_t OFF_TTI = 1572864;
constexpr size_t OFF_QSR = 2097152;                 // rel q (src) [(n*hw), b, 64]
constexpr size_t OFF_QSI = OFF_QSR + 65536;
constexpr size_t OFF_QTR = OFF_QSI + 65536;
constexpr size_t OFF_QTI = OFF_QTR + 65536;
constexpr size_t OFF_AS  = OFF_QTI + 65536;         // self-attn A (src) [nb,256,256]
constexpr size_t OFF_AT  = OFF_AS + 262144;
constexpr size_t OFF_YSR = OFF_AT + 262144;         // src + attn out (then mem after scale)
constexpr size_t OFF_YSI = OFF_YSR + 524288;
constexpr size_t OFF_YTR = OFF_YSI + 524288;        // tgt + attn out (then x after scale)
constexpr size_t OFF_YTI = OFF_YTR + 524288;
constexpr size_t OFF_QCR = OFF_YTI + 524288;        // cross q [l,b,128]
constexpr size_t OFF_QCI = OFF_QCR + 131072;
constexpr size_t OFF_KCR = OFF_QCI + 131072;
constexpr size_t OFF_KCI = OFF_KCR + 131072;
constexpr size_t OFF_AC  = OFF_KCI + 131072;        // cross scores -> A [b,512,512]
constexpr size_t OFF_T3R = OFF_AC + 524288;         // t3 (then z after combine)
constexpr size_t OFF_T3I = OFF_T3R + 524288;
constexpr size_t OFF_MR  = OFF_T3I + 524288;        // mask scalar [b,512]
constexpr size_t OFF_MI  = OFF_MR + 1024;
constexpr size_t OFF_P1  = OFF_MI + 1024;           // partials (16 qty-groups x 32)
constexpr size_t OFF_P2  = OFF_P1 + 512;
constexpr size_t OFF_P3  = OFF_P2 + 512;
constexpr size_t OFF_S1  = OFF_P3 + 256;            // scales
constexpr size_t OFF_S2  = OFF_S1 + 16;
constexpr size_t OFF_SZ  = OFF_S2 + 16;

// ---- block reductions ----
template<int NT>
__device__ __forceinline__ float blk_sum(float v, float* sh) {
  int tid = threadIdx.x;
  sh[tid] = v; __syncthreads();
  #pragma unroll
  for (int s = NT/2; s > 0; s >>= 1) { if (tid < s) sh[tid] += sh[tid+s]; __syncthreads(); }
  float r = sh[0]; __syncthreads(); return r;
}
template<int NT>
__device__ __forceinline__ float blk_max(float v, float* sh) {
  int tid = threadIdx.x;
  sh[tid] = v; __syncthreads();
  #pragma unroll
  for (int s = NT/2; s > 0; s >>= 1) { if (tid < s) sh[tid] = fmaxf(sh[tid], sh[tid+s]); __syncthreads(); }
  float r = sh[0]; __syncthreads(); return r;
}

// ---- 1: tokenize transpose: [n,b,d,hw] -> [(n*hw),b,d] ----
__global__ void k_transpose(const float* sR, const float* sI, const float* tR, const float* tI, float* ws) {
  int which = blockIdx.y;
  const float* in = (which==0)? sR : (which==1)? sI : (which==2)? tR : tI;
  float* out = ws + ((which==0)? OFF_TSR : (which==1)? OFF_TSI : (which==2)? OFF_TTR : OFF_TTI);
  int bx = blockIdx.x;               // 128 = nb(4)*dt(8)*pt(4)
  int pt = bx & 3, dt = (bx>>2)&7, nb = bx>>5;
  int ni = nb>>1, bi = nb&1;
  __shared__ float tile[64][65];
  int tid = threadIdx.x;
  int p0 = pt*64, d0 = dt*64;
  #pragma unroll
  for (int it=0; it<16; ++it) {
    int i = it*256 + tid; int row = i>>6, col = i&63;   // row=d_local, col=p_local
    tile[row][col] = in[(size_t)(nb*D_ + d0+row)*HW_ + p0+col];
  }
  __syncthreads();
  #pragma unroll
  for (int it=0; it<16; ++it) {
    int i = it*256 + tid; int row = i>>6, col = i&63;   // row=p_local, col=d_local
    out[(size_t)((ni*HW_ + p0+row)*B_ + bi)*D_ + d0+col] = tile[col][row];
  }
}

// ---- 2: rel q projection + cnorm (src & tgt) ----
__global__ void k_qrel(float* ws, const float* WK) {
  int idx = blockIdx.x;              // 2048
  int which = idx >> 10; int t = idx & 1023;
  int r = t >> 1, bi = t & 1;
  const float* Tr = ws + (which ? OFF_TTR : OFF_TSR);
  const float* Ti = ws + (which ? OFF_TTI : OFF_TSI);
  float* Qr = ws + (which ? OFF_QTR : OFF_QSR);
  float* Qi = ws + (which ? OFF_QTI : OFF_QSI);
  int tid = threadIdx.x;             // 128
  int kk = tid & 63, isIm = tid >> 6;
  const float* x = (isIm ? Ti : Tr) + (size_t)(r*B_ + bi)*D_;
  const float4* x4 = (const float4*)x;
  float acc = 0.f;
  #pragma unroll 8
  for (int d4 = 0; d4 < 128; ++d4) {
    float4 xv = x4[d4]; int d = d4*4;
    acc += xv.x*WK[(d+0)*DK_+kk] + xv.y*WK[(d+1)*DK_+kk] + xv.z*WK[(d+2)*DK_+kk] + xv.w*WK[(d+3)*DK_+kk];
  }
  __shared__ float sh[128];
  float ss = blk_sum<128>(acc*acc, sh);
  float q = acc / sqrtf(ss + 1e-12f);
  (isIm ? Qi : Qr)[(size_t)(r*B_ + bi)*DK_ + kk] = q;
}

// ---- 3: rel self-attn scores + softmax -> A  (reads the 268MB embeddings) ----
__global__ void k_selfattn(float* ws, const float* esr, const float* esi, const float* etr, const float* eti) {
  int idx = blockIdx.x;              // 2048
  int which = idx >> 10; int rest = idx & 1023;
  int iq = rest & 255; int nb = rest >> 8;
  int ni = nb>>1, bi = nb&1;
  const float* Qr = ws + (which ? OFF_QTR : OFF_QSR);
  const float* Qi = ws + (which ? OFF_QTI : OFF_QSI);
  const float* er = which ? etr : esr;
  const float* ei = which ? eti : esi;
  float* A = ws + (which ? OFF_AT : OFF_AS);
  __shared__ float qqr[64], qqi[64], sh[256];
  int tid = threadIdx.x;             // 256, = key index l
  int tokq = ni*HW_ + iq;
  if (tid < 64)       qqr[tid]     = Qr[(size_t)(tokq*B_ + bi)*DK_ + tid];
  else if (tid < 128) qqi[tid-64]  = Qi[(size_t)(tokq*B_ + bi)*DK_ + (tid-64)];
  __syncthreads();
  int l = tid;
  const float4* qlr4 = (const float4*)(Qr + (size_t)((ni*HW_ + l)*B_ + bi)*DK_);
  const float4* qli4 = (const float4*)(Qi + (size_t)((ni*HW_ + l)*B_ + bi)*DK_);
  float acc = 0.f;
  #pragma unroll
  for (int k4 = 0; k4 < 16; ++k4) {
    float4 r4 = qlr4[k4], i4 = qli4[k4];
    int k = k4*4;
    acc += qqr[k]*r4.x + qqr[k+1]*r4.y + qqr[k+2]*r4.z + qqr[k+3]*r4.w
         + qqi[k]*i4.x + qqi[k+1]*i4.y + qqi[k+2]*i4.z + qqi[k+3]*i4.w;
  }
  size_t eb = (size_t)nb*4194304 + (size_t)iq*256 + l;  // + k*65536
  #pragma unroll 4
  for (int k = 0; k < 64; ++k)
    acc += qqr[k]*er[eb + (size_t)k*65536] + qqi[k]*ei[eb + (size_t)k*65536];
  float s = acc * 30.f;
  float m = blk_max<256>(s, sh);
  float e = __expf(s - m);
  float sum = blk_sum<256>(e, sh);
  A[(size_t)nb*65536 + (size_t)iq*256 + l] = e / sum;
}

// ---- 4: Y = tok + A @ tok  (64x64 tiles, r & i together) ----
__global__ void __launch_bounds__(256) k_selfapply(float* ws) {
  int bx = blockIdx.x;               // 256 = which(2)*nb(4)*qt(4)*dt(8)
  int dt = bx & 7, qt = (bx>>3)&3, nb = (bx>>5)&3, which = bx>>7;
  int ni = nb>>1, bi = nb&1;
  const float* A  = ws + (which ? OFF_AT : OFF_AS) + (size_t)nb*65536;
  const float* Xr = ws + (which ? OFF_TTR : OFF_TSR);
  const float* Xi = ws + (which ? OFF_TTI : OFF_TSI);
  float* Yr = ws + (which ? OFF_YTR : OFF_YSR);
  float* Yi = ws + (which ? OFF_YTI : OFF_YSI);
  __shared__ float As[64][65], Xrs[64][65], Xis[64][65];
  int tid = threadIdx.x, ty = tid>>4, tx = tid&15;
  int ty4 = ty*4, tx4 = tx*4;
  float ar[4][4] = {}, ai[4][4] = {};
  for (int lc = 0; lc < 4; ++lc) {
    #pragma unroll
    for (int it = 0; it < 16; ++it) {
      int i = it*256 + tid; int row = i>>6, col = i&63;
      As[row][col] = A[(size_t)(qt*64+row)*256 + lc*64+col];
      size_t xb = (size_t)((ni*HW_ + lc*64+row)*B_ + bi)*D_ + dt*64+col;
      Xrs[row][col] = Xr[xb]; Xis[row][col] = Xi[xb];
    }
    __syncthreads();
    #pragma unroll 8
    for (int kk = 0; kk < 64; ++kk) {
      #pragma unroll
      for (int i = 0; i < 4; ++i) {
        float a = As[ty4+i][kk];
        #pragma unroll
        for (int j = 0; j < 4; ++j) {
          ar[i][j] += a * Xrs[kk][tx4+j];
          ai[i][j] += a * Xis[kk][tx4+j];
        }
      }
    }
    __syncthreads();
  }
  #pragma unroll
  for (int i = 0; i < 4; ++i)
    #pragma unroll
    for (int j = 0; j < 4; ++j) {
      size_t o = (size_t)((ni*HW_ + qt*64 + ty4+i)*B_ + bi)*D_ + dt*64 + tx4+j;
      Yr[o] = Xr[o] + ar[i][j];
      Yi[o] = Xi[o] + ai[i][j];
    }
}

// ---- 5: ss = sum(Y^2) per (n,b) for the 4 Y arrays ----
__global__ void k_reduce4(float* ws) {
  int qy = blockIdx.y;
  const float* a = ws + ((qy==0)? OFF_YSR : (qy==1)? OFF_YSI : (qy==2)? OFF_YTR : OFF_YTI);
  int g = blockIdx.x / NBLK_, blk = blockIdx.x % NBLK_;
  int ni = g>>1, bi = g&1;
  int tid = threadIdx.x;
  float acc = 0.f;
  for (int p = blk; p < HW_; p += NBLK_) {
    const float* row = a + (size_t)((ni*HW_ + p)*B_ + bi)*D_;
    for (int d = tid; d < D_; d += 256) { float v = row[d]; acc += v*v; }
  }
  __shared__ float sh[256];
  float s = blk_sum<256>(acc, sh);
  if (!tid) ws[OFF_P1 + (size_t)(qy*G_ + g)*NBLK_ + blk] = s;
}

// ---- finalize: scale = 4*rsqrt(ss + 1e-5) ----
__global__ void k_finalize(const float* part, float* scales, int nq) {
  int t = threadIdx.x;
  if (t < nq) {
    float ss = 0.f;
    for (int j = 0; j < NBLK_; ++j) ss += part[t*NBLK_ + j];
    scales[t] = 4.f * rsqrtf(ss + 1e-5f);
  }
}

// ---- 7: Y *= scale  (mem / x) ----
__global__ void k_applyscale(float* ws, const float* scales) {
  int qy = blockIdx.y;
  float* a = ws + ((qy==0)? OFF_YSR : (qy==1)? OFF_YSI : (qy==2)? OFF_YTR : OFF_YTI);
  int idx4 = blockIdx.x*256 + threadIdx.x;   // 131072 float4s
  int elem = idx4*4;
  int bi = (elem / D_) & 1;
  int r = elem >> 10;
  int ni = r >> 8;
  float s = scales[qy*G_ + ni*2 + bi];
  float4 v = ((float4*)a)[idx4];
  v.x *= s; v.y *= s; v.z *= s; v.w *= s;
  ((float4*)a)[idx4] = v;
}

// ---- 8: cross q/k projection + cnorm ----
__global__ void k_crossproj(float* ws, const float* W) {
  int idx = blockIdx.x;              // 2048
  int isK = idx >> 10; int t = idx & 1023;
  int r = t >> 1, bi = t & 1;
  const float* inR = ws + (isK ? OFF_YSR : OFF_YTR);
  const float* inI = ws + (isK ? OFF_YSI : OFF_YTI);
  float* oR = ws + (isK ? OFF_KCR : OFF_QCR);
  float* oI = ws + (isK ? OFF_KCI : OFF_QCI);
  int tid = threadIdx.x;             // 128 = k
  const float4* xr4 = (const float4*)(inR + (size_t)(r*B_ + bi)*D_);
  const float4* xi4 = (const float4*)(inI + (size_t)(r*B_ + bi)*D_);
  float aR = 0.f, aI = 0.f;
  #pragma unroll 8
  for (int d4 = 0; d4 < 128; ++d4) {
    float4 rv = xr4[d4], iv = xi4[d4]; int d = d4*4;
    float w0 = W[(d+0)*DKC_ + tid], w1 = W[(d+1)*DKC_ + tid], w2 = W[(d+2)*DKC_ + tid], w3 = W[(d+3)*DKC_ + tid];
    aR += rv.x*w0 + rv.y*w1 + rv.z*w2 + rv.w*w3;
    aI += iv.x*w0 + iv.y*w1 + iv.z*w2 + iv.w*w3;
  }
  __shared__ float sh[128];
  float ss = blk_sum<128>(aR*aR + aI*aI, sh);
  float inv = 1.f / sqrtf(ss + 1e-12f);
  oR[(size_t)(r*B_ + bi)*DKC_ + tid] = aR * inv;
  oI[(size_t)(r*B_ + bi)*DKC_ + tid] = aI * inv;
}

// ---- 9: raw cross scores S = Qr Kr^T + Qi Ki^T ----
__global__ void __launch_bounds__(256) k_crossscore(float* ws) {
  int bx = blockIdx.x;               // 128 = b(2)*qt(8)*lt(8)
  int lt = bx & 7, qt = (bx>>3)&7, bi = bx>>6;
  const float* Qr = ws + OFF_QCR; const float* Qi = ws + OFF_QCI;
  const float* Kr = ws + OFF_KCR; const float* Ki = ws + OFF_KCI;
  float* S = ws + OFF_AC + (size_t)bi*262144;
  __shared__ float Qrs[64][33], Qis[64][33], Krs[64][33], Kis[64][33];
  int tid = threadIdx.x, ty = tid>>4, tx = tid&15;
  int ty4 = ty*4, tx4 = tx*4;
  float acc[4][4] = {};
  for (int kc = 0; kc < 4; ++kc) {
    #pragma unroll
    for (int it = 0; it < 8; ++it) {
      int i = it*256 + tid; int row = i>>5, col = i&31;
      Qrs[row][col] = Qr[(size_t)((qt*64+row)*B_ + bi)*DKC_ + kc*32 + col];
      Qis[row][col] = Qi[(size_t)((qt*64+row)*B_ + bi)*DKC_ + kc*32 + col];
      Krs[row][col] = Kr[(size_t)((lt*64+row)*B_ + bi)*DKC_ + kc*32 + col];
      Kis[row][col] = Ki[(size_t)((lt*64+row)*B_ + bi)*DKC_ + kc*32 + col];
    }
    __syncthreads();
    #pragma unroll 8
    for (int kk = 0; kk < 32; ++kk) {
      #pragma unroll
      for (int i = 0; i < 4; ++i) {
        float qr = Qrs[ty4+i][kk], qi = Qis[ty4+i][kk];
        #pragma unroll
        for (int j = 0; j < 4; ++j)
          acc[i][j] += qr*Krs[tx4+j][kk] + qi*Kis[tx4+j][kk];
      }
    }
    __syncthreads();
  }
  #pragma unroll
  for (int i = 0; i < 4; ++i)
    #pragma unroll
    for (int j = 0; j < 4; ++j)
      S[(size_t)(qt*64+ty4+i)*512 + lt*64+tx4+j] = acc[i][j];
}

// ---- 10: softmax per row (in-place) + mask scalars m = A @ pos ----
__global__ void k_softmaxrow(float* ws, const float* posr, const float* posi) {
  int bx = blockIdx.x;               // 1024 = b*512
  int bi = bx >> 9, iq = bx & 511;
  float* row = ws + OFF_AC + (size_t)bi*262144 + (size_t)iq*512;
  int tid = threadIdx.x;             // 256
  float s0 = row[tid]*30.f, s1 = row[tid+256]*30.f;
  __shared__ float sh[256];
  float m = blk_max<256>(fmaxf(s0, s1), sh);
  float e0 = __expf(s0 - m), e1 = __expf(s1 - m);
  float sum = blk_sum<256>(e0 + e1, sh);
  float inv = 1.f / sum;
  float a0 = e0*inv, a1 = e1*inv;
  row[tid] = a0; row[tid+256] = a1;
  float pr0 = posr[bi*HW_ + tid],        pr1 = posr[(B_+bi)*HW_ + tid];
  float pi0 = posi[bi*HW_ + tid],        pi1 = posi[(B_+bi)*HW_ + tid];
  float mr = blk_sum<256>(a0*pr0 + a1*pr1, sh);
  float mi = blk_sum<256>(a0*pi0 + a1*pi1, sh);
  if (!tid) { ws[OFF_MR + bi*512 + iq] = mr; ws[OFF_MI + bi*512 + iq] = mi; }
}

// ---- 11: t3 = A @ (mem * pos) ----
__global__ void __launch_bounds__(256) k_crossapply(float* ws, const float* posr, const float* posi) {
  int bx = blockIdx.x;               // 128 = b(2)*qt(8)*dt(8)
  int dt = bx & 7, qt = (bx>>3)&7, bi = bx>>6;
  const float* A  = ws + OFF_AC + (size_t)bi*262144;
  const float* Mr = ws + OFF_YSR; const float* Mi = ws + OFF_YSI;
  float* Tr = ws + OFF_T3R; float* Ti = ws + OFF_T3I;
  __shared__ float As[64][65], Vrs[64][65], Vis[64][65];
  int tid = threadIdx.x, ty = tid>>4, tx = tid&15;
  int ty4 = ty*4, tx4 = tx*4;
  float ar[4][4] = {}, ai[4][4] = {};
  for (int lc = 0; lc < 8; ++lc) {
    #pragma unroll
    for (int it = 0; it < 16; ++it) {
      int i = it*256 + tid; int row = i>>6, col = i&63;
      As[row][col] = A[(size_t)(qt*64+row)*512 + lc*64+col];
      int l = lc*64 + row;
      int nil = l >> 8, pl = l & 255;
      float pvr = posr[(nil*B_ + bi)*HW_ + pl];
      float pvi = posi[(nil*B_ + bi)*HW_ + pl];
      size_t vb = (size_t)(l*B_ + bi)*D_ + dt*64 + col;
      Vrs[row][col] = Mr[vb] * pvr;
      Vis[row][col] = Mi[vb] * pvi;
    }
    __syncthreads();
    #pragma unroll 8
    for (int kk = 0; kk < 64; ++kk) {
      #pragma unroll
      for (int i = 0; i < 4; ++i) {
        float a = As[ty4+i][kk];
        #pragma unroll
        for (int j = 0; j < 4; ++j) {
          ar[i][j] += a * Vrs[kk][tx4+j];
          ai[i][j] += a * Vis[kk][tx4+j];
        }
      }
    }
    __syncthreads();
  }
  #pragma unroll
  for (int i = 0; i < 4; ++i)
    #pragma unroll
    for (int j = 0; j < 4; ++j) {
      size_t o = (size_t)((qt*64+ty4+i)*B_ + bi)*D_ + dt*64 + tx4+j;
      Tr[o] = ar[i][j];
      Ti[o] = ai[i][j];
    }
}

// ---- 12: ss for (x*m)^2 (r,i) and (x+t3)^2 (r,i) ----
__global__ void k_reducey24(float* ws) {
  int qy = blockIdx.y;
  int g = blockIdx.x / NBLK_, blk = blockIdx.x % NBLK_;
  int ni = g>>1, bi = g&1;
  const float* X  = ws + ((qy==0 || qy==2) ? OFF_YTR : OFF_YTI);
  const float* T3 = ws + ((qy==2) ? OFF_T3R : OFF_T3I);
  const float* M  = ws + ((qy==0) ? OFF_MR : OFF_MI);
  int tid = threadIdx.x;
  float acc = 0.f;
  for (int p = blk; p < HW_; p += NBLK_) {
    int l = ni*HW_ + p;
    size_t rb = (size_t)(l*B_ + bi)*D_;
    if (qy < 2) {
      float m = M[bi*512 + l];
      for (int d = tid; d < D_; d += 256) { float v = X[rb+d]*m; acc += v*v; }
    } else {
      for (int d = tid; d < D_; d += 256) { float v = X[rb+d] + T3[rb+d]; acc += v*v; }
    }
  }
  __shared__ float sh[256];
  float s = blk_sum<256>(acc, sh);
  if (!tid) ws[OFF_P2 + (size_t)(qy*G_ + g)*NBLK_ + blk] = s;
}

// ---- 14: z = a2*(x*m) + a4*(x+t3) (in-place into t3) + ss(z) partials ----
__global__ void k_combine(float* ws, const float* scales2) {
  int y = blockIdx.y;                // 0=r, 1=i
  int g = blockIdx.x / NBLK_, blk = blockIdx.x % NBLK_;
  int ni = g>>1, bi = g&1;
  const float* X = ws + (y ? OFF_YTI : OFF_YTR);
  float* T3 = ws + (y ? OFF_T3I : OFF_T3R);
  const float* M = ws + (y ? OFF_MI : OFF_MR);
  float a2 = scales2[y*G_ + g], a4 = scales2[(2+y)*G_ + g];
  int tid = threadIdx.x;
  float acc = 0.f;
  for (int p = blk; p < HW_; p += NBLK_) {
    int l = ni*HW_ + p;
    float m = M[bi*512 + l];
    size_t rb = (size_t)(l*B_ + bi)*D_;
    for (int d = tid; d < D_; d += 256) {
      float x = X[rb+d];
      float z = a2*(x*m) + a4*(x + T3[rb+d]);
      T3[rb+d] = z;
      acc += z*z;
    }
  }
  __shared__ float sh[256];
  float s = blk_sum<256>(acc, sh);
  if (!tid) ws[OFF_P3 + (size_t)(y*G_ + g)*NBLK_ + blk] = s;
}

// ---- 16: out = z*scale; feat = transpose(out) ----
__global__ void k_final(float* ws, const float* scalesZ, float* out) {
  int y = blockIdx.y;                // 0=r, 1=i
  int bx = blockIdx.x;               // 128 = nb(4)*dt(8)*pt(4)
  int pt = bx & 3, dt = (bx>>2)&7, nb = bx>>5;
  int ni = nb>>1, bi = nb&1;
  const float* Z = ws + (y ? OFF_T3I : OFF_T3R);
  float s = scalesZ[y*G_ + nb];
  float* o1 = out + (size_t)y*524288;        // out_r / out_i
  float* o2 = out + (size_t)(2+y)*524288;    // feat_r / feat_i
  __shared__ float tile[64][65];
  int tid = threadIdx.x;
  int p0 = pt*64, d0 = dt*64;
  #pragma unroll
  for (int it = 0; it < 16; ++it) {
    int i = it*256 + tid; int row = i>>6, col = i&63;   // row=p_local, col=d_local
    size_t idx = (size_t)((ni*HW_ + p0+row)*B_ + bi)*D_ + d0+col;
    float v = Z[idx] * s;
    o1[idx] = v;
    tile[row][col] = v;
  }
  __syncthreads();
  #pragma unroll
  for (int it = 0; it < 16; ++it) {
    int i = it*256 + tid; int row = i>>6, col = i&63;   // row=d_local, col=p_local
    o2[(size_t)(nb*D_ + d0+row)*HW_ + p0+col] = tile[col][row];
  }
}

extern "C" void kernel_launch(void* const* d_in, const int* in_sizes, int n_in,
                              void* d_out, int out_size, void* d_ws, size_t ws_size,
                              hipStream_t stream) {
  const float* srcR = (const float*)d_in[0];
  const float* srcI = (const float*)d_in[1];
  const float* tgtR = (const float*)d_in[2];
  const float* tgtI = (const float*)d_in[3];
  const float* esr  = (const float*)d_in[4];
  const float* esi  = (const float*)d_in[5];
  const float* etr  = (const float*)d_in[6];
  const float* eti  = (const float*)d_in[7];
  const float* posR = (const float*)d_in[8];
  const float* posI = (const float*)d_in[9];
  const float* WKrel   = (const float*)d_in[10];
  const float* WKcross = (const float*)d_in[11];
  float* ws  = (float*)d_ws;
  float* out = (float*)d_out;

  k_transpose <<<dim3(128,4), 256, 0, stream>>>(srcR, srcI, tgtR, tgtI, ws);
  k_qrel      <<<2048, 128, 0, stream>>>(ws, WKrel);
  k_selfattn  <<<2048, 256, 0, stream>>>(ws, esr, esi, etr, eti);
  k_selfapply <<<256, 256, 0, stream>>>(ws);
  k_reduce4   <<<dim3(G_*NBLK_,4), 256, 0, stream>>>(ws);
  k_finalize  <<<1, 64, 0, stream>>>(ws + OFF_P1, ws + OFF_S1, 16);
  k_applyscale<<<dim3(512,4), 256, 0, stream>>>(ws, ws + OFF_S1);
  k_crossproj <<<2048, 128, 0, stream>>>(ws, WKcross);
  k_crossscore<<<128, 256, 0, stream>>>(ws);
  k_softmaxrow<<<1024, 256, 0, stream>>>(ws, posR, posI);
  k_crossapply<<<128, 256, 0, stream>>>(ws, posR, posI);
  k_reducey24 <<<dim3(G_*NBLK_,4), 256, 0, stream>>>(ws);
  k_finalize  <<<1, 64, 0, stream>>>(ws + OFF_P2, ws + OFF_S2, 16);
  k_combine   <<<dim3(G_*NBLK_,2), 256, 0, stream>>>(ws, ws + OFF_S2);
  k_finalize  <<<1, 64, 0, stream>>>(ws + OFF_P3, ws + OFF_SZ, 8);
  k_final     <<<dim3(128,2), 256, 0, stream>>>(ws, ws + OFF_SZ, out);
}

// Round 2
// 281.344 us; speedup vs baseline: 1.4203x; 1.4203x over previous
//
#include <hip/hip_runtime.h>
#include <cstdint>
#include <cstddef>

#define N_ 2
#define B_ 2
#define D_ 512
#define HW_ 256
#define DK_ 64
#define DKC_ 128
#define G_ 4
#define NBLK_ 32

// ---- workspace offsets (in floats) ----
constexpr size_t OFF_TSR = 0;                       // src_real tokens [(n*hw), b, d]  (reused as T3r partial kc=1)
constexpr size_t OFF_TSI = 524288;                  // (reused as T3i partial kc=1)
constexpr size_t OFF_TTR = 1048576;
constexpr size_t OFF_TTI = 1572864;
constexpr size_t OFF_QSR = 2097152;                 // rel q (src) [(n*hw), b, 64]
constexpr size_t OFF_QSI = OFF_QSR + 65536;
constexpr size_t OFF_QTR = OFF_QSI + 65536;
constexpr size_t OFF_QTI = OFF_QTR + 65536;
constexpr size_t OFF_AS  = OFF_QTI + 65536;         // self-attn A (src) [nb,256,256]
constexpr size_t OFF_AT  = OFF_AS + 262144;
constexpr size_t OFF_YSR = OFF_AT + 262144;         // src + attn out (then mem after scale)
constexpr size_t OFF_YSI = OFF_YSR + 524288;
constexpr size_t OFF_YTR = OFF_YSI + 524288;        // tgt + attn out (then x after scale)
constexpr size_t OFF_YTI = OFF_YTR + 524288;
constexpr size_t OFF_QCR = OFF_YTI + 524288;        // cross q [l,b,128]
constexpr size_t OFF_QCI = OFF_QCR + 131072;
constexpr size_t OFF_KCR = OFF_QCI + 131072;
constexpr size_t OFF_KCI = OFF_KCR + 131072;
constexpr size_t OFF_AC  = OFF_KCI + 131072;        // cross scores -> A [b,512,512]
constexpr size_t OFF_T3R = OFF_AC + 524288;         // t3 partial kc=0 (then z after combine)
constexpr size_t OFF_T3I = OFF_T3R + 524288;
constexpr size_t OFF_MR  = OFF_T3I + 524288;        // mask scalar [b,512]
constexpr size_t OFF_MI  = OFF_MR + 1024;
constexpr size_t OFF_P1  = OFF_MI + 1024;           // partials (16 qty-groups x 32)
constexpr size_t OFF_P2  = OFF_P1 + 512;
constexpr size_t OFF_P3  = OFF_P2 + 512;
constexpr size_t OFF_S1  = OFF_P3 + 256;            // scales
constexpr size_t OFF_S2  = OFF_S1 + 16;
constexpr size_t OFF_SZ  = OFF_S2 + 16;

// ---- reductions ----
template<int NT>
__device__ __forceinline__ float blk_sum(float v, float* sh) {
  int tid = threadIdx.x;
  sh[tid] = v; __syncthreads();
  #pragma unroll
  for (int s = NT/2; s > 0; s >>= 1) { if (tid < s) sh[tid] += sh[tid+s]; __syncthreads(); }
  float r = sh[0]; __syncthreads(); return r;
}
template<int NT>
__device__ __forceinline__ float blk_max(float v, float* sh) {
  int tid = threadIdx.x;
  sh[tid] = v; __syncthreads();
  #pragma unroll
  for (int s = NT/2; s > 0; s >>= 1) { if (tid < s) sh[tid] = fmaxf(sh[tid], sh[tid+s]); __syncthreads(); }
  float r = sh[0]; __syncthreads(); return r;
}
__device__ __forceinline__ float wave_max(float v) {
  #pragma unroll
  for (int o = 32; o; o >>= 1) v = fmaxf(v, __shfl_xor(v, o, 64));
  return v;
}
__device__ __forceinline__ float wave_sum(float v) {
  #pragma unroll
  for (int o = 32; o; o >>= 1) v += __shfl_xor(v, o, 64);
  return v;
}

// ---- 1: tokenize transpose: [n,b,d,hw] -> [(n*hw),b,d] ----
__global__ void k_transpose(const float* sR, const float* sI, const float* tR, const float* tI, float* ws) {
  int which = blockIdx.y;
  const float* in = (which==0)? sR : (which==1)? sI : (which==2)? tR : tI;
  float* out = ws + ((which==0)? OFF_TSR : (which==1)? OFF_TSI : (which==2)? OFF_TTR : OFF_TTI);
  int bx = blockIdx.x;               // 128 = nb(4)*dt(8)*pt(4)
  int pt = bx & 3, dt = (bx>>2)&7, nb = bx>>5;
  int ni = nb>>1, bi = nb&1;
  __shared__ float tile[64][65];
  int tid = threadIdx.x;
  int p0 = pt*64, d0 = dt*64;
  #pragma unroll
  for (int it=0; it<16; ++it) {
    int i = it*256 + tid; int row = i>>6, col = i&63;   // row=d_local, col=p_local
    tile[row][col] = in[(size_t)(nb*D_ + d0+row)*HW_ + p0+col];
  }
  __syncthreads();
  #pragma unroll
  for (int it=0; it<16; ++it) {
    int i = it*256 + tid; int row = i>>6, col = i&63;   // row=p_local, col=d_local
    out[(size_t)((ni*HW_ + p0+row)*B_ + bi)*D_ + d0+col] = tile[col][row];
  }
}

// ---- 2: rel q projection + cnorm (src & tgt) ----
__global__ void k_qrel(float* ws, const float* WK) {
  int idx = blockIdx.x;              // 2048
  int which = idx >> 10; int t = idx & 1023;
  int r = t >> 1, bi = t & 1;
  const float* Tr = ws + (which ? OFF_TTR : OFF_TSR);
  const float* Ti = ws + (which ? OFF_TTI : OFF_TSI);
  float* Qr = ws + (which ? OFF_QTR : OFF_QSR);
  float* Qi = ws + (which ? OFF_QTI : OFF_QSI);
  int tid = threadIdx.x;             // 128
  int kk = tid & 63, isIm = tid >> 6;
  const float* x = (isIm ? Ti : Tr) + (size_t)(r*B_ + bi)*D_;
  const float4* x4 = (const float4*)x;
  float acc = 0.f;
  #pragma unroll 8
  for (int d4 = 0; d4 < 128; ++d4) {
    float4 xv = x4[d4]; int d = d4*4;
    acc += xv.x*WK[(d+0)*DK_+kk] + xv.y*WK[(d+1)*DK_+kk] + xv.z*WK[(d+2)*DK_+kk] + xv.w*WK[(d+3)*DK_+kk];
  }
  __shared__ float sh[128];
  float ss = blk_sum<128>(acc*acc, sh);
  float q = acc / sqrtf(ss + 1e-12f);
  (isIm ? Qi : Qr)[(size_t)(r*B_ + bi)*DK_ + kk] = q;
}

// ---- 3: rel self-attn scores + softmax -> A  (wave per q-row, float4 over l) ----
__global__ void __launch_bounds__(256) k_selfattn(float* ws, const float* esr, const float* esi,
                                                  const float* etr, const float* eti) {
  int idx = blockIdx.x;              // 512 = which(2)*nb(4)*qg(64)
  int qg = idx & 63, nb = (idx>>6)&3, which = idx>>8;
  int ni = nb>>1, bi = nb&1;
  const float* Qr = ws + (which ? OFF_QTR : OFF_QSR);
  const float* Qi = ws + (which ? OFF_QTI : OFF_QSI);
  const float* er = which ? etr : esr;
  const float* ei = which ? eti : esi;
  float* A = ws + (which ? OFF_AT : OFF_AS);
  __shared__ float qq[4][128];
  int tid = threadIdx.x;
  {
    int row = tid>>6, k = tid&63;
    int tok = ni*HW_ + qg*4 + row;
    qq[row][k]    = Qr[(size_t)(tok*B_ + bi)*DK_ + k];
    qq[row][64+k] = Qi[(size_t)(tok*B_ + bi)*DK_ + k];
  }
  __syncthreads();
  int w = tid>>6, lane = tid&63;
  int iq = qg*4 + w;
  int l0 = lane*4;
  float acc[4] = {0.f,0.f,0.f,0.f};
  // QK gram part
  const float4* qqr4 = (const float4*)&qq[w][0];
  const float4* qqi4 = (const float4*)&qq[w][64];
  #pragma unroll 4
  for (int k4 = 0; k4 < 16; ++k4) {
    float4 qr = qqr4[k4], qi = qqi4[k4];
    #pragma unroll
    for (int j = 0; j < 4; ++j) {
      float4 xr = *(const float4*)&Qr[(size_t)((ni*HW_ + l0+j)*B_ + bi)*DK_ + k4*4];
      float4 xi = *(const float4*)&Qi[(size_t)((ni*HW_ + l0+j)*B_ + bi)*DK_ + k4*4];
      acc[j] += qr.x*xr.x + qr.y*xr.y + qr.z*xr.z + qr.w*xr.w
              + qi.x*xi.x + qi.y*xi.y + qi.z*xi.z + qi.w*xi.w;
    }
  }
  // embedding part (the 268 MB)
  size_t eb = (size_t)nb*4194304 + (size_t)iq*256 + l0;
  #pragma unroll 4
  for (int k = 0; k < 64; ++k) {
    float4 e4r = *(const float4*)&er[eb + (size_t)k*65536];
    float4 e4i = *(const float4*)&ei[eb + (size_t)k*65536];
    float qr = qq[w][k], qi = qq[w][64+k];
    acc[0] += qr*e4r.x + qi*e4i.x;
    acc[1] += qr*e4r.y + qi*e4i.y;
    acc[2] += qr*e4r.z + qi*e4i.z;
    acc[3] += qr*e4r.w + qi*e4i.w;
  }
  float s0 = acc[0]*30.f, s1 = acc[1]*30.f, s2 = acc[2]*30.f, s3 = acc[3]*30.f;
  float m = wave_max(fmaxf(fmaxf(s0,s1), fmaxf(s2,s3)));
  float e0 = __expf(s0-m), e1 = __expf(s1-m), e2 = __expf(s2-m), e3 = __expf(s3-m);
  float inv = 1.f / wave_sum(e0+e1+e2+e3);
  float4 outv = make_float4(e0*inv, e1*inv, e2*inv, e3*inv);
  *(float4*)&A[(size_t)nb*65536 + (size_t)iq*256 + l0] = outv;
}

// ---- 4: Y = tok + A @ tok  (32x64 tiles, 128 thr, r & i together) ----
__global__ void __launch_bounds__(128) k_selfapply(float* ws) {
  int bx = blockIdx.x;               // 512 = which(2)*nb(4)*qt(8)*dt(8)
  int dt = bx & 7, qt = (bx>>3)&7, nb = (bx>>6)&3, which = bx>>8;
  int ni = nb>>1, bi = nb&1;
  const float* A  = ws + (which ? OFF_AT : OFF_AS) + (size_t)nb*65536;
  const float* Xr = ws + (which ? OFF_TTR : OFF_TSR);
  const float* Xi = ws + (which ? OFF_TTI : OFF_TSI);
  float* Yr = ws + (which ? OFF_YTR : OFF_YSR);
  float* Yi = ws + (which ? OFF_YTI : OFF_YSI);
  __shared__ float As[32][33], Xrs[32][68], Xis[32][68];
  int tid = threadIdx.x, ty = tid>>4, tx = tid&15;
  int ty4 = ty*4, tx4 = tx*4;
  float ar[4][4] = {}, ai[4][4] = {};
  for (int c = 0; c < 8; ++c) {
    #pragma unroll
    for (int it = 0; it < 8; ++it) {
      int i = it*128 + tid; int row = i>>5, col = i&31;
      As[row][col] = A[(size_t)(qt*32+row)*256 + c*32+col];
    }
    #pragma unroll
    for (int it = 0; it < 16; ++it) {
      int i = it*128 + tid; int row = i>>6, col = i&63;
      size_t xb = (size_t)((ni*HW_ + c*32+row)*B_ + bi)*D_ + dt*64+col;
      Xrs[row][col] = Xr[xb]; Xis[row][col] = Xi[xb];
    }
    __syncthreads();
    #pragma unroll
    for (int kk = 0; kk < 32; ++kk) {
      float4 vr = *(const float4*)&Xrs[kk][tx4];
      float4 vi = *(const float4*)&Xis[kk][tx4];
      #pragma unroll
      for (int i = 0; i < 4; ++i) {
        float a = As[ty4+i][kk];
        ar[i][0] += a*vr.x; ar[i][1] += a*vr.y; ar[i][2] += a*vr.z; ar[i][3] += a*vr.w;
        ai[i][0] += a*vi.x; ai[i][1] += a*vi.y; ai[i][2] += a*vi.z; ai[i][3] += a*vi.w;
      }
    }
    __syncthreads();
  }
  #pragma unroll
  for (int i = 0; i < 4; ++i) {
    size_t o = (size_t)((ni*HW_ + qt*32 + ty4+i)*B_ + bi)*D_ + dt*64 + tx4;
    #pragma unroll
    for (int j = 0; j < 4; ++j) { Yr[o+j] = Xr[o+j] + ar[i][j]; Yi[o+j] = Xi[o+j] + ai[i][j]; }
  }
}

// ---- 5: ss = sum(Y^2) per (n,b) for the 4 Y arrays ----
__global__ void k_reduce4(float* ws) {
  int qy = blockIdx.y;
  const float* a = ws + ((qy==0)? OFF_YSR : (qy==1)? OFF_YSI : (qy==2)? OFF_YTR : OFF_YTI);
  int g = blockIdx.x / NBLK_, blk = blockIdx.x % NBLK_;
  int ni = g>>1, bi = g&1;
  int tid = threadIdx.x;
  float acc = 0.f;
  for (int p = blk; p < HW_; p += NBLK_) {
    const float* row = a + (size_t)((ni*HW_ + p)*B_ + bi)*D_;
    for (int d = tid; d < D_; d += 256) { float v = row[d]; acc += v*v; }
  }
  __shared__ float sh[256];
  float s = blk_sum<256>(acc, sh);
  if (!tid) ws[OFF_P1 + (size_t)(qy*G_ + g)*NBLK_ + blk] = s;
}

// ---- finalize: scale = 4*rsqrt(ss + 1e-5) ----
__global__ void k_finalize(const float* part, float* scales, int nq) {
  int t = threadIdx.x;
  if (t < nq) {
    float ss = 0.f;
    for (int j = 0; j < NBLK_; ++j) ss += part[t*NBLK_ + j];
    scales[t] = 4.f * rsqrtf(ss + 1e-5f);
  }
}

// ---- 7: Y *= scale  (mem / x) ----
__global__ void k_applyscale(float* ws, const float* scales) {
  int qy = blockIdx.y;
  float* a = ws + ((qy==0)? OFF_YSR : (qy==1)? OFF_YSI : (qy==2)? OFF_YTR : OFF_YTI);
  int idx4 = blockIdx.x*256 + threadIdx.x;
  int elem = idx4*4;
  int bi = (elem / D_) & 1;
  int r = elem >> 10;
  int ni = r >> 8;
  float s = scales[qy*G_ + ni*2 + bi];
  float4 v = ((float4*)a)[idx4];
  v.x *= s; v.y *= s; v.z *= s; v.w *= s;
  ((float4*)a)[idx4] = v;
}

// ---- 8: cross q/k projection + cnorm ----
__global__ void k_crossproj(float* ws, const float* W) {
  int idx = blockIdx.x;              // 2048
  int isK = idx >> 10; int t = idx & 1023;
  int r = t >> 1, bi = t & 1;
  const float* inR = ws + (isK ? OFF_YSR : OFF_YTR);
  const float* inI = ws + (isK ? OFF_YSI : OFF_YTI);
  float* oR = ws + (isK ? OFF_KCR : OFF_QCR);
  float* oI = ws + (isK ? OFF_KCI : OFF_QCI);
  int tid = threadIdx.x;             // 128 = k
  const float4* xr4 = (const float4*)(inR + (size_t)(r*B_ + bi)*D_);
  const float4* xi4 = (const float4*)(inI + (size_t)(r*B_ + bi)*D_);
  float aR = 0.f, aI = 0.f;
  #pragma unroll 8
  for (int d4 = 0; d4 < 128; ++d4) {
    float4 rv = xr4[d4], iv = xi4[d4]; int d = d4*4;
    float w0 = W[(d+0)*DKC_ + tid], w1 = W[(d+1)*DKC_ + tid], w2 = W[(d+2)*DKC_ + tid], w3 = W[(d+3)*DKC_ + tid];
    aR += rv.x*w0 + rv.y*w1 + rv.z*w2 + rv.w*w3;
    aI += iv.x*w0 + iv.y*w1 + iv.z*w2 + iv.w*w3;
  }
  __shared__ float sh[128];
  float ss = blk_sum<128>(aR*aR + aI*aI, sh);
  float inv = 1.f / sqrtf(ss + 1e-12f);
  oR[(size_t)(r*B_ + bi)*DKC_ + tid] = aR * inv;
  oI[(size_t)(r*B_ + bi)*DKC_ + tid] = aI * inv;
}

// ---- 9: raw cross scores S = Qr Kr^T + Qi Ki^T  (32x64 tiles) ----
__global__ void __launch_bounds__(128) k_crossscore(float* ws) {
  int bx = blockIdx.x;               // 256 = bi(2)*qt(16)*lt(8)
  int lt = bx & 7, qt = (bx>>3)&15, bi = bx>>7;
  const float* Qr = ws + OFF_QCR; const float* Qi = ws + OFF_QCI;
  const float* Kr = ws + OFF_KCR; const float* Ki = ws + OFF_KCI;
  float* S = ws + OFF_AC + (size_t)bi*262144;
  __shared__ float Qrs[32][33], Qis[32][33], Krs[32][68], Kis[32][68];
  int tid = threadIdx.x, ty = tid>>4, tx = tid&15;
  int ty4 = ty*4, tx4 = tx*4;
  float acc[4][4] = {};
  for (int c = 0; c < 4; ++c) {
    #pragma unroll
    for (int it = 0; it < 8; ++it) {
      int i = it*128 + tid; int row = i>>5, col = i&31;
      Qrs[row][col] = Qr[(size_t)((qt*32+row)*B_ + bi)*DKC_ + c*32 + col];
      Qis[row][col] = Qi[(size_t)((qt*32+row)*B_ + bi)*DKC_ + c*32 + col];
    }
    #pragma unroll
    for (int it = 0; it < 16; ++it) {
      int i = it*128 + tid; int kk = i&31, col = i>>5;
      Krs[kk][col] = Kr[(size_t)((lt*64+col)*B_ + bi)*DKC_ + c*32 + kk];
      Kis[kk][col] = Ki[(size_t)((lt*64+col)*B_ + bi)*DKC_ + c*32 + kk];
    }
    __syncthreads();
    #pragma unroll
    for (int kk = 0; kk < 32; ++kk) {
      float4 kr = *(const float4*)&Krs[kk][tx4];
      float4 ki = *(const float4*)&Kis[kk][tx4];
      #pragma unroll
      for (int i = 0; i < 4; ++i) {
        float qr = Qrs[ty4+i][kk], qi = Qis[ty4+i][kk];
        acc[i][0] += qr*kr.x + qi*ki.x;
        acc[i][1] += qr*kr.y + qi*ki.y;
        acc[i][2] += qr*kr.z + qi*ki.z;
        acc[i][3] += qr*kr.w + qi*ki.w;
      }
    }
    __syncthreads();
  }
  #pragma unroll
  for (int i = 0; i < 4; ++i)
    #pragma unroll
    for (int j = 0; j < 4; ++j)
      S[(size_t)(qt*32+ty4+i)*512 + lt*64+tx4+j] = acc[i][j];
}

// ---- 10: softmax per row (in-place) + mask scalars m = A @ pos ----
__global__ void k_softmaxrow(float* ws, const float* posr, const float* posi) {
  int bx = blockIdx.x;               // 1024 = b*512
  int bi = bx >> 9, iq = bx & 511;
  float* row = ws + OFF_AC + (size_t)bi*262144 + (size_t)iq*512;
  int tid = threadIdx.x;             // 256
  float s0 = row[tid]*30.f, s1 = row[tid+256]*30.f;
  __shared__ float sh[256];
  float m = blk_max<256>(fmaxf(s0, s1), sh);
  float e0 = __expf(s0 - m), e1 = __expf(s1 - m);
  float sum = blk_sum<256>(e0 + e1, sh);
  float inv = 1.f / sum;
  float a0 = e0*inv, a1 = e1*inv;
  row[tid] = a0; row[tid+256] = a1;
  float pr0 = posr[bi*HW_ + tid],        pr1 = posr[(B_+bi)*HW_ + tid];
  float pi0 = posi[bi*HW_ + tid],        pi1 = posi[(B_+bi)*HW_ + tid];
  float mr = blk_sum<256>(a0*pr0 + a1*pr1, sh);
  float mi = blk_sum<256>(a0*pi0 + a1*pi1, sh);
  if (!tid) { ws[OFF_MR + bi*512 + iq] = mr; ws[OFF_MI + bi*512 + iq] = mi; }
}

// ---- 11: t3 = A @ (mem * pos), split-K=2, partials ----
__global__ void __launch_bounds__(128) k_crossapply(float* ws, const float* posr, const float* posi) {
  int bx = blockIdx.x;               // 512 = kc(2)*bi(2)*qt(16)*dt(8)
  int dt = bx & 7, qt = (bx>>3)&15, bi = (bx>>7)&1, kc = bx>>8;
  const float* A  = ws + OFF_AC + (size_t)bi*262144;
  const float* Mr = ws + OFF_YSR; const float* Mi = ws + OFF_YSI;
  float* Pr = ws + (kc ? OFF_TSR : OFF_T3R);
  float* Pi = ws + (kc ? OFF_TSI : OFF_T3I);
  __shared__ float As[32][33], Vrs[32][68], Vis[32][68];
  int tid = threadIdx.x, ty = tid>>4, tx = tid&15;
  int ty4 = ty*4, tx4 = tx*4;
  float ar[4][4] = {}, ai[4][4] = {};
  for (int c = 0; c < 8; ++c) {
    int kb = kc*256 + c*32;
    #pragma unroll
    for (int it = 0; it < 8; ++it) {
      int i = it*128 + tid; int row = i>>5, col = i&31;
      As[row][col] = A[(size_t)(qt*32+row)*512 + kb+col];
    }
    #pragma unroll
    for (int it = 0; it < 16; ++it) {
      int i = it*128 + tid; int row = i>>6, col = i&63;
      int l = kb + row; int nil = l>>8, pl = l&255;
      float pvr = posr[(nil*B_ + bi)*HW_ + pl];
      float pvi = posi[(nil*B_ + bi)*HW_ + pl];
      size_t vb = (size_t)(l*B_ + bi)*D_ + dt*64+col;
      Vrs[row][col] = Mr[vb] * pvr;
      Vis[row][col] = Mi[vb] * pvi;
    }
    __syncthreads();
    #pragma unroll
    for (int kk = 0; kk < 32; ++kk) {
      float4 vr = *(const float4*)&Vrs[kk][tx4];
      float4 vi = *(const float4*)&Vis[kk][tx4];
      #pragma unroll
      for (int i = 0; i < 4; ++i) {
        float a = As[ty4+i][kk];
        ar[i][0] += a*vr.x; ar[i][1] += a*vr.y; ar[i][2] += a*vr.z; ar[i][3] += a*vr.w;
        ai[i][0] += a*vi.x; ai[i][1] += a*vi.y; ai[i][2] += a*vi.z; ai[i][3] += a*vi.w;
      }
    }
    __syncthreads();
  }
  #pragma unroll
  for (int i = 0; i < 4; ++i) {
    size_t o = (size_t)((qt*32+ty4+i)*B_ + bi)*D_ + dt*64 + tx4;
    #pragma unroll
    for (int j = 0; j < 4; ++j) { Pr[o+j] = ar[i][j]; Pi[o+j] = ai[i][j]; }
  }
}

// ---- 12: ss for (x*m)^2 (r,i) and (x+t3)^2 (r,i); t3 = sum of 2 partials ----
__global__ void k_reducey24(float* ws) {
  int qy = blockIdx.y;
  int g = blockIdx.x / NBLK_, blk = blockIdx.x % NBLK_;
  int ni = g>>1, bi = g&1;
  const float* X   = ws + ((qy==0 || qy==2) ? OFF_YTR : OFF_YTI);
  const float* T3a = ws + ((qy==2) ? OFF_T3R : OFF_T3I);
  const float* T3b = ws + ((qy==2) ? OFF_TSR : OFF_TSI);
  const float* M   = ws + ((qy==0) ? OFF_MR : OFF_MI);
  int tid = threadIdx.x;
  float acc = 0.f;
  for (int p = blk; p < HW_; p += NBLK_) {
    int l = ni*HW_ + p;
    size_t rb = (size_t)(l*B_ + bi)*D_;
    if (qy < 2) {
      float m = M[bi*512 + l];
      for (int d = tid; d < D_; d += 256) { float v = X[rb+d]*m; acc += v*v; }
    } else {
      for (int d = tid; d < D_; d += 256) { float v = X[rb+d] + T3a[rb+d] + T3b[rb+d]; acc += v*v; }
    }
  }
  __shared__ float sh[256];
  float s = blk_sum<256>(acc, sh);
  if (!tid) ws[OFF_P2 + (size_t)(qy*G_ + g)*NBLK_ + blk] = s;
}

// ---- 14: z = a2*(x*m) + a4*(x+t3) (into T3a) + ss(z) partials ----
__global__ void k_combine(float* ws, const float* scales2) {
  int y = blockIdx.y;                // 0=r, 1=i
  int g = blockIdx.x / NBLK_, blk = blockIdx.x % NBLK_;
  int ni = g>>1, bi = g&1;
  const float* X   = ws + (y ? OFF_YTI : OFF_YTR);
  float* T3a       = ws + (y ? OFF_T3I : OFF_T3R);
  const float* T3b = ws + (y ? OFF_TSI : OFF_TSR);
  const float* M   = ws + (y ? OFF_MI : OFF_MR);
  float a2 = scales2[y*G_ + g], a4 = scales2[(2+y)*G_ + g];
  int tid = threadIdx.x;
  float acc = 0.f;
  for (int p = blk; p < HW_; p += NBLK_) {
    int l = ni*HW_ + p;
    float m = M[bi*512 + l];
    size_t rb = (size_t)(l*B_ + bi)*D_;
    for (int d = tid; d < D_; d += 256) {
      float x = X[rb+d];
      float z = a2*(x*m) + a4*(x + T3a[rb+d] + T3b[rb+d]);
      T3a[rb+d] = z;
      acc += z*z;
    }
  }
  __shared__ float sh[256];
  float s = blk_sum<256>(acc, sh);
  if (!tid) ws[OFF_P3 + (size_t)(y*G_ + g)*NBLK_ + blk] = s;
}

// ---- 16: out = z*scale; feat = transpose(out) ----
__global__ void k_final(float* ws, const float* scalesZ, float* out) {
  int y = blockIdx.y;                // 0=r, 1=i
  int bx = blockIdx.x;               // 128 = nb(4)*dt(8)*pt(4)
  int pt = bx & 3, dt = (bx>>2)&7, nb = bx>>5;
  int ni = nb>>1, bi = nb&1;
  const float* Z = ws + (y ? OFF_T3I : OFF_T3R);
  float s = scalesZ[y*G_ + nb];
  float* o1 = out + (size_t)y*524288;        // out_r / out_i
  float* o2 = out + (size_t)(2+y)*524288;    // feat_r / feat_i
  __shared__ float tile[64][65];
  int tid = threadIdx.x;
  int p0 = pt*64, d0 = dt*64;
  #pragma unroll
  for (int it = 0; it < 16; ++it) {
    int i = it*256 + tid; int row = i>>6, col = i&63;   // row=p_local, col=d_local
    size_t idx = (size_t)((ni*HW_ + p0+row)*B_ + bi)*D_ + d0+col;
    float v = Z[idx] * s;
    o1[idx] = v;
    tile[row][col] = v;
  }
  __syncthreads();
  #pragma unroll
  for (int it = 0; it < 16; ++it) {
    int i = it*256 + tid; int row = i>>6, col = i&63;   // row=d_local, col=p_local
    o2[(size_t)(nb*D_ + d0+row)*HW_ + p0+col] = tile[col][row];
  }
}

extern "C" void kernel_launch(void* const* d_in, const int* in_sizes, int n_in,
                              void* d_out, int out_size, void* d_ws, size_t ws_size,
                              hipStream_t stream) {
  const float* srcR = (const float*)d_in[0];
  const float* srcI = (const float*)d_in[1];
  const float* tgtR = (const float*)d_in[2];
  const float* tgtI = (const float*)d_in[3];
  const float* esr  = (const float*)d_in[4];
  const float* esi  = (const float*)d_in[5];
  const float* etr  = (const float*)d_in[6];
  const float* eti  = (const float*)d_in[7];
  const float* posR = (const float*)d_in[8];
  const float* posI = (const float*)d_in[9];
  const float* WKrel   = (const float*)d_in[10];
  const float* WKcross = (const float*)d_in[11];
  float* ws  = (float*)d_ws;
  float* out = (float*)d_out;

  k_transpose <<<dim3(128,4), 256, 0, stream>>>(srcR, srcI, tgtR, tgtI, ws);
  k_qrel      <<<2048, 128, 0, stream>>>(ws, WKrel);
  k_selfattn  <<<512, 256, 0, stream>>>(ws, esr, esi, etr, eti);
  k_selfapply <<<512, 128, 0, stream>>>(ws);
  k_reduce4   <<<dim3(G_*NBLK_,4), 256, 0, stream>>>(ws);
  k_finalize  <<<1, 64, 0, stream>>>(ws + OFF_P1, ws + OFF_S1, 16);
  k_applyscale<<<dim3(512,4), 256, 0, stream>>>(ws, ws + OFF_S1);
  k_crossproj <<<2048, 128, 0, stream>>>(ws, WKcross);
  k_crossscore<<<256, 128, 0, stream>>>(ws);
  k_softmaxrow<<<1024, 256, 0, stream>>>(ws, posR, posI);
  k_crossapply<<<512, 128, 0, stream>>>(ws, posR, posI);
  k_reducey24 <<<dim3(G_*NBLK_,4), 256, 0, stream>>>(ws);
  k_finalize  <<<1, 64, 0, stream>>>(ws + OFF_P2, ws + OFF_S2, 16);
  k_combine   <<<dim3(G_*NBLK_,2), 256, 0, stream>>>(ws, ws + OFF_S2);
  k_finalize  <<<1, 64, 0, stream>>>(ws + OFF_P3, ws + OFF_SZ, 8);
  k_final     <<<dim3(128,2), 256, 0, stream>>>(ws, ws + OFF_SZ, out);
}

// Round 3
// 274.953 us; speedup vs baseline: 1.4533x; 1.0232x over previous
//
#include <hip/hip_runtime.h>
#include <cstdint>
#include <cstddef>

#define N_ 2
#define B_ 2
#define D_ 512
#define HW_ 256
#define DK_ 64
#define DKC_ 128
#define G_ 4
#define NBLK_ 32

// ---- workspace offsets (in floats) ----
constexpr size_t OFF_TSR = 0;                       // src_real tokens [(n*hw), b, d]  (reused as T3r partial kc=1)
constexpr size_t OFF_TSI = 524288;                  // (reused as T3i partial kc=1)
constexpr size_t OFF_TTR = 1048576;
constexpr size_t OFF_TTI = 1572864;
constexpr size_t OFF_QSR = 2097152;                 // rel q (src) [(n*hw), b, 64]
constexpr size_t OFF_QSI = OFF_QSR + 65536;
constexpr size_t OFF_QTR = OFF_QSI + 65536;
constexpr size_t OFF_QTI = OFF_QTR + 65536;
constexpr size_t OFF_AS  = OFF_QTI + 65536;         // self-attn A (src) [nb,256,256]
constexpr size_t OFF_AT  = OFF_AS + 262144;
constexpr size_t OFF_YSR = OFF_AT + 262144;         // src + attn out (then mem after scale)
constexpr size_t OFF_YSI = OFF_YSR + 524288;
constexpr size_t OFF_YTR = OFF_YSI + 524288;        // tgt + attn out (then x after scale)
constexpr size_t OFF_YTI = OFF_YTR + 524288;
constexpr size_t OFF_QCR = OFF_YTI + 524288;        // cross q [l,b,128]
constexpr size_t OFF_QCI = OFF_QCR + 131072;
constexpr size_t OFF_KCR = OFF_QCI + 131072;
constexpr size_t OFF_KCI = OFF_KCR + 131072;
constexpr size_t OFF_AC  = OFF_KCI + 131072;        // cross scores -> A [b,512,512]
constexpr size_t OFF_T3R = OFF_AC + 524288;         // t3 partial kc=0 (then z after combine)
constexpr size_t OFF_T3I = OFF_T3R + 524288;
constexpr size_t OFF_MR  = OFF_T3I + 524288;        // mask scalar [b,512]
constexpr size_t OFF_MI  = OFF_MR + 1024;
constexpr size_t OFF_P1  = OFF_MI + 1024;           // partials (16 qty-groups x 32)
constexpr size_t OFF_P2  = OFF_P1 + 512;
constexpr size_t OFF_P3  = OFF_P2 + 512;
constexpr size_t OFF_S1  = OFF_P3 + 256;            // scales
constexpr size_t OFF_S2  = OFF_S1 + 16;
constexpr size_t OFF_SZ  = OFF_S2 + 16;

// ---- reductions ----
template<int NT>
__device__ __forceinline__ float blk_sum(float v, float* sh) {
  int tid = threadIdx.x;
  sh[tid] = v; __syncthreads();
  #pragma unroll
  for (int s = NT/2; s > 0; s >>= 1) { if (tid < s) sh[tid] += sh[tid+s]; __syncthreads(); }
  float r = sh[0]; __syncthreads(); return r;
}
template<int NT>
__device__ __forceinline__ float blk_max(float v, float* sh) {
  int tid = threadIdx.x;
  sh[tid] = v; __syncthreads();
  #pragma unroll
  for (int s = NT/2; s > 0; s >>= 1) { if (tid < s) sh[tid] = fmaxf(sh[tid], sh[tid+s]); __syncthreads(); }
  float r = sh[0]; __syncthreads(); return r;
}

// ---- 1: tokenize transpose: [n,b,d,hw] -> [(n*hw),b,d] ----
__global__ void k_transpose(const float* sR, const float* sI, const float* tR, const float* tI, float* ws) {
  int which = blockIdx.y;
  const float* in = (which==0)? sR : (which==1)? sI : (which==2)? tR : tI;
  float* out = ws + ((which==0)? OFF_TSR : (which==1)? OFF_TSI : (which==2)? OFF_TTR : OFF_TTI);
  int bx = blockIdx.x;               // 128 = nb(4)*dt(8)*pt(4)
  int pt = bx & 3, dt = (bx>>2)&7, nb = bx>>5;
  int ni = nb>>1, bi = nb&1;
  __shared__ float tile[64][65];
  int tid = threadIdx.x;
  int p0 = pt*64, d0 = dt*64;
  #pragma unroll
  for (int it=0; it<16; ++it) {
    int i = it*256 + tid; int row = i>>6, col = i&63;   // row=d_local, col=p_local
    tile[row][col] = in[(size_t)(nb*D_ + d0+row)*HW_ + p0+col];
  }
  __syncthreads();
  #pragma unroll
  for (int it=0; it<16; ++it) {
    int i = it*256 + tid; int row = i>>6, col = i&63;   // row=p_local, col=d_local
    out[(size_t)((ni*HW_ + p0+row)*B_ + bi)*D_ + d0+col] = tile[col][row];
  }
}

// ---- 2: rel q projection + cnorm (src & tgt) ----
__global__ void k_qrel(float* ws, const float* WK) {
  int idx = blockIdx.x;              // 2048
  int which = idx >> 10; int t = idx & 1023;
  int r = t >> 1, bi = t & 1;
  const float* Tr = ws + (which ? OFF_TTR : OFF_TSR);
  const float* Ti = ws + (which ? OFF_TTI : OFF_TSI);
  float* Qr = ws + (which ? OFF_QTR : OFF_QSR);
  float* Qi = ws + (which ? OFF_QTI : OFF_QSI);
  int tid = threadIdx.x;             // 128
  int kk = tid & 63, isIm = tid >> 6;
  const float* x = (isIm ? Ti : Tr) + (size_t)(r*B_ + bi)*D_;
  const float4* x4 = (const float4*)x;
  float acc = 0.f;
  #pragma unroll 8
  for (int d4 = 0; d4 < 128; ++d4) {
    float4 xv = x4[d4]; int d = d4*4;
    acc += xv.x*WK[(d+0)*DK_+kk] + xv.y*WK[(d+1)*DK_+kk] + xv.z*WK[(d+2)*DK_+kk] + xv.w*WK[(d+3)*DK_+kk];
  }
  __shared__ float sh[128];
  float ss = blk_sum<128>(acc*acc, sh);
  float q = acc / sqrtf(ss + 1e-12f);
  (isIm ? Qi : Qr)[(size_t)(r*B_ + bi)*DK_ + kk] = q;
}

// ---- 2b: gram scores G = Qr Qr^T + Qi Qi^T, written into A buffers ----
__global__ void __launch_bounds__(128) k_gram(float* ws) {
  int bx = blockIdx.x;               // 256 = which(2)*nb(4)*qt(8)*lt(4)
  int lt = bx & 3, qt = (bx>>2)&7, nb = (bx>>5)&3, which = bx>>7;
  int ni = nb>>1, bi = nb&1;
  const float* Qr = ws + (which ? OFF_QTR : OFF_QSR);
  const float* Qi = ws + (which ? OFF_QTI : OFF_QSI);
  float* A = ws + (which ? OFF_AT : OFF_AS) + (size_t)nb*65536;
  __shared__ float Qrs[32][33], Qis[32][33], Krs[32][68], Kis[32][68];
  int tid = threadIdx.x, ty = tid>>4, tx = tid&15;
  int ty4 = ty*4, tx4 = tx*4;
  float acc[4][4] = {};
  for (int c = 0; c < 2; ++c) {
    #pragma unroll
    for (int it = 0; it < 8; ++it) {
      int i = it*128 + tid; int row = i>>5, col = i&31;
      size_t qa = (size_t)((ni*HW_ + qt*32+row)*B_ + bi)*DK_ + c*32 + col;
      Qrs[row][col] = Qr[qa];
      Qis[row][col] = Qi[qa];
    }
    #pragma unroll
    for (int it = 0; it < 16; ++it) {
      int i = it*128 + tid; int kk = i&31, col = i>>5;
      size_t ka = (size_t)((ni*HW_ + lt*64+col)*B_ + bi)*DK_ + c*32 + kk;
      Krs[kk][col] = Qr[ka];
      Kis[kk][col] = Qi[ka];
    }
    __syncthreads();
    #pragma unroll
    for (int kk = 0; kk < 32; ++kk) {
      float4 kr = *(const float4*)&Krs[kk][tx4];
      float4 ki = *(const float4*)&Kis[kk][tx4];
      #pragma unroll
      for (int i = 0; i < 4; ++i) {
        float qr = Qrs[ty4+i][kk], qi = Qis[ty4+i][kk];
        acc[i][0] += qr*kr.x + qi*ki.x;
        acc[i][1] += qr*kr.y + qi*ki.y;
        acc[i][2] += qr*kr.z + qi*ki.z;
        acc[i][3] += qr*kr.w + qi*ki.w;
      }
    }
    __syncthreads();
  }
  #pragma unroll
  for (int i = 0; i < 4; ++i)
    #pragma unroll
    for (int j = 0; j < 4; ++j)
      A[(size_t)(qt*32+ty4+i)*256 + lt*64+tx4+j] = acc[i][j];
}

// ---- 3: rel self-attn emb scores + softmax (gram pre-seeded in A) ----
__global__ void __launch_bounds__(256) k_selfattn(float* ws, const float* esr, const float* esi,
                                                  const float* etr, const float* eti) {
  int idx = blockIdx.x;              // 2048 = which(2)*nb(4)*iq(256)
  int iq = idx & 255, nb = (idx>>8)&3, which = idx>>10;
  int ni = nb>>1, bi = nb&1;
  const float* Qr = ws + (which ? OFF_QTR : OFF_QSR);
  const float* Qi = ws + (which ? OFF_QTI : OFF_QSI);
  const float* er = which ? etr : esr;
  const float* ei = which ? eti : esi;
  float* Arow = ws + (which ? OFF_AT : OFF_AS) + (size_t)nb*65536 + (size_t)iq*256;
  int tid = threadIdx.x, w = tid>>6, lane = tid&63;
  // lane 0..15 hold Qr[k-chunk], 16..31 hold Qi[k-chunk]
  size_t qbase = (size_t)((ni*HW_ + iq)*B_ + bi)*DK_ + w*16;
  int kl = lane & 15;
  float qv = ((lane & 16) ? Qi : Qr)[qbase + kl];
  int l0 = lane*4;
  float a0=0.f, a1=0.f, a2=0.f, a3=0.f;
  size_t eb = (size_t)nb*4194304 + (size_t)(w*16)*65536 + (size_t)iq*256 + l0;
  #pragma unroll 4
  for (int kk = 0; kk < 16; ++kk) {
    float4 e4r = *(const float4*)&er[eb + (size_t)kk*65536];
    float4 e4i = *(const float4*)&ei[eb + (size_t)kk*65536];
    float fr = __shfl(qv, kk);
    float fi = __shfl(qv, 16+kk);
    a0 += fr*e4r.x + fi*e4i.x;
    a1 += fr*e4r.y + fi*e4i.y;
    a2 += fr*e4r.z + fi*e4i.z;
    a3 += fr*e4r.w + fi*e4i.w;
  }
  __shared__ float part[4][256];
  __shared__ float sh[256];
  *(float4*)&part[w][l0] = make_float4(a0,a1,a2,a3);
  __syncthreads();
  float s = (part[0][tid]+part[1][tid]+part[2][tid]+part[3][tid] + Arow[tid]) * 30.f;
  float m = blk_max<256>(s, sh);
  float e = __expf(s - m);
  float sum = blk_sum<256>(e, sh);
  Arow[tid] = e / sum;
}

// ---- 4: Y = tok + A @ tok  (32x64 tiles, 128 thr, r & i together) ----
__global__ void __launch_bounds__(128) k_selfapply(float* ws) {
  int bx = blockIdx.x;               // 512 = which(2)*nb(4)*qt(8)*dt(8)
  int dt = bx & 7, qt = (bx>>3)&7, nb = (bx>>6)&3, which = bx>>8;
  int ni = nb>>1, bi = nb&1;
  const float* A  = ws + (which ? OFF_AT : OFF_AS) + (size_t)nb*65536;
  const float* Xr = ws + (which ? OFF_TTR : OFF_TSR);
  const float* Xi = ws + (which ? OFF_TTI : OFF_TSI);
  float* Yr = ws + (which ? OFF_YTR : OFF_YSR);
  float* Yi = ws + (which ? OFF_YTI : OFF_YSI);
  __shared__ float As[32][33], Xrs[32][68], Xis[32][68];
  int tid = threadIdx.x, ty = tid>>4, tx = tid&15;
  int ty4 = ty*4, tx4 = tx*4;
  float ar[4][4] = {}, ai[4][4] = {};
  for (int c = 0; c < 8; ++c) {
    #pragma unroll
    for (int it = 0; it < 8; ++it) {
      int i = it*128 + tid; int row = i>>5, col = i&31;
      As[row][col] = A[(size_t)(qt*32+row)*256 + c*32+col];
    }
    #pragma unroll
    for (int it = 0; it < 16; ++it) {
      int i = it*128 + tid; int row = i>>6, col = i&63;
      size_t xb = (size_t)((ni*HW_ + c*32+row)*B_ + bi)*D_ + dt*64+col;
      Xrs[row][col] = Xr[xb]; Xis[row][col] = Xi[xb];
    }
    __syncthreads();
    #pragma unroll
    for (int kk = 0; kk < 32; ++kk) {
      float4 vr = *(const float4*)&Xrs[kk][tx4];
      float4 vi = *(const float4*)&Xis[kk][tx4];
      #pragma unroll
      for (int i = 0; i < 4; ++i) {
        float a = As[ty4+i][kk];
        ar[i][0] += a*vr.x; ar[i][1] += a*vr.y; ar[i][2] += a*vr.z; ar[i][3] += a*vr.w;
        ai[i][0] += a*vi.x; ai[i][1] += a*vi.y; ai[i][2] += a*vi.z; ai[i][3] += a*vi.w;
      }
    }
    __syncthreads();
  }
  #pragma unroll
  for (int i = 0; i < 4; ++i) {
    size_t o = (size_t)((ni*HW_ + qt*32 + ty4+i)*B_ + bi)*D_ + dt*64 + tx4;
    #pragma unroll
    for (int j = 0; j < 4; ++j) { Yr[o+j] = Xr[o+j] + ar[i][j]; Yi[o+j] = Xi[o+j] + ai[i][j]; }
  }
}

// ---- 5: ss = sum(Y^2) per (n,b) for the 4 Y arrays ----
__global__ void k_reduce4(float* ws) {
  int qy = blockIdx.y;
  const float* a = ws + ((qy==0)? OFF_YSR : (qy==1)? OFF_YSI : (qy==2)? OFF_YTR : OFF_YTI);
  int g = blockIdx.x / NBLK_, blk = blockIdx.x % NBLK_;
  int ni = g>>1, bi = g&1;
  int tid = threadIdx.x;
  float acc = 0.f;
  for (int p = blk; p < HW_; p += NBLK_) {
    const float* row = a + (size_t)((ni*HW_ + p)*B_ + bi)*D_;
    for (int d = tid; d < D_; d += 256) { float v = row[d]; acc += v*v; }
  }
  __shared__ float sh[256];
  float s = blk_sum<256>(acc, sh);
  if (!tid) ws[OFF_P1 + (size_t)(qy*G_ + g)*NBLK_ + blk] = s;
}

// ---- finalize: scale = 4*rsqrt(ss + 1e-5) ----
__global__ void k_finalize(const float* part, float* scales, int nq) {
  int t = threadIdx.x;
  if (t < nq) {
    float ss = 0.f;
    for (int j = 0; j < NBLK_; ++j) ss += part[t*NBLK_ + j];
    scales[t] = 4.f * rsqrtf(ss + 1e-5f);
  }
}

// ---- 7: Y *= scale  (mem / x) ----
__global__ void k_applyscale(float* ws, const float* scales) {
  int qy = blockIdx.y;
  float* a = ws + ((qy==0)? OFF_YSR : (qy==1)? OFF_YSI : (qy==2)? OFF_YTR : OFF_YTI);
  int idx4 = blockIdx.x*256 + threadIdx.x;
  int elem = idx4*4;
  int bi = (elem / D_) & 1;
  int r = elem >> 10;
  int ni = r >> 8;
  float s = scales[qy*G_ + ni*2 + bi];
  float4 v = ((float4*)a)[idx4];
  v.x *= s; v.y *= s; v.z *= s; v.w *= s;
  ((float4*)a)[idx4] = v;
}

// ---- 8: cross q/k projection + cnorm ----
__global__ void k_crossproj(float* ws, const float* W) {
  int idx = blockIdx.x;              // 2048
  int isK = idx >> 10; int t = idx & 1023;
  int r = t >> 1, bi = t & 1;
  const float* inR = ws + (isK ? OFF_YSR : OFF_YTR);
  const float* inI = ws + (isK ? OFF_YSI : OFF_YTI);
  float* oR = ws + (isK ? OFF_KCR : OFF_QCR);
  float* oI = ws + (isK ? OFF_KCI : OFF_QCI);
  int tid = threadIdx.x;             // 128 = k
  const float4* xr4 = (const float4*)(inR + (size_t)(r*B_ + bi)*D_);
  const float4* xi4 = (const float4*)(inI + (size_t)(r*B_ + bi)*D_);
  float aR = 0.f, aI = 0.f;
  #pragma unroll 8
  for (int d4 = 0; d4 < 128; ++d4) {
    float4 rv = xr4[d4], iv = xi4[d4]; int d = d4*4;
    float w0 = W[(d+0)*DKC_ + tid], w1 = W[(d+1)*DKC_ + tid], w2 = W[(d+2)*DKC_ + tid], w3 = W[(d+3)*DKC_ + tid];
    aR += rv.x*w0 + rv.y*w1 + rv.z*w2 + rv.w*w3;
    aI += iv.x*w0 + iv.y*w1 + iv.z*w2 + iv.w*w3;
  }
  __shared__ float sh[128];
  float ss = blk_sum<128>(aR*aR + aI*aI, sh);
  float inv = 1.f / sqrtf(ss + 1e-12f);
  oR[(size_t)(r*B_ + bi)*DKC_ + tid] = aR * inv;
  oI[(size_t)(r*B_ + bi)*DKC_ + tid] = aI * inv;
}

// ---- 9: raw cross scores S = Qr Kr^T + Qi Ki^T  (32x64 tiles) ----
__global__ void __launch_bounds__(128) k_crossscore(float* ws) {
  int bx = blockIdx.x;               // 256 = bi(2)*qt(16)*lt(8)
  int lt = bx & 7, qt = (bx>>3)&15, bi = bx>>7;
  const float* Qr = ws + OFF_QCR; const float* Qi = ws + OFF_QCI;
  const float* Kr = ws + OFF_KCR; const float* Ki = ws + OFF_KCI;
  float* S = ws + OFF_AC + (size_t)bi*262144;
  __shared__ float Qrs[32][33], Qis[32][33], Krs[32][68], Kis[32][68];
  int tid = threadIdx.x, ty = tid>>4, tx = tid&15;
  int ty4 = ty*4, tx4 = tx*4;
  float acc[4][4] = {};
  for (int c = 0; c < 4; ++c) {
    #pragma unroll
    for (int it = 0; it < 8; ++it) {
      int i = it*128 + tid; int row = i>>5, col = i&31;
      Qrs[row][col] = Qr[(size_t)((qt*32+row)*B_ + bi)*DKC_ + c*32 + col];
      Qis[row][col] = Qi[(size_t)((qt*32+row)*B_ + bi)*DKC_ + c*32 + col];
    }
    #pragma unroll
    for (int it = 0; it < 16; ++it) {
      int i = it*128 + tid; int kk = i&31, col = i>>5;
      Krs[kk][col] = Kr[(size_t)((lt*64+col)*B_ + bi)*DKC_ + c*32 + kk];
      Kis[kk][col] = Ki[(size_t)((lt*64+col)*B_ + bi)*DKC_ + c*32 + kk];
    }
    __syncthreads();
    #pragma unroll
    for (int kk = 0; kk < 32; ++kk) {
      float4 kr = *(const float4*)&Krs[kk][tx4];
      float4 ki = *(const float4*)&Kis[kk][tx4];
      #pragma unroll
      for (int i = 0; i < 4; ++i) {
        float qr = Qrs[ty4+i][kk], qi = Qis[ty4+i][kk];
        acc[i][0] += qr*kr.x + qi*ki.x;
        acc[i][1] += qr*kr.y + qi*ki.y;
        acc[i][2] += qr*kr.z + qi*ki.z;
        acc[i][3] += qr*kr.w + qi*ki.w;
      }
    }
    __syncthreads();
  }
  #pragma unroll
  for (int i = 0; i < 4; ++i)
    #pragma unroll
    for (int j = 0; j < 4; ++j)
      S[(size_t)(qt*32+ty4+i)*512 + lt*64+tx4+j] = acc[i][j];
}

// ---- 10: softmax per row (in-place) + mask scalars m = A @ pos ----
__global__ void k_softmaxrow(float* ws, const float* posr, const float* posi) {
  int bx = blockIdx.x;               // 1024 = b*512
  int bi = bx >> 9, iq = bx & 511;
  float* row = ws + OFF_AC + (size_t)bi*262144 + (size_t)iq*512;
  int tid = threadIdx.x;             // 256
  float s0 = row[tid]*30.f, s1 = row[tid+256]*30.f;
  __shared__ float sh[256];
  float m = blk_max<256>(fmaxf(s0, s1), sh);
  float e0 = __expf(s0 - m), e1 = __expf(s1 - m);
  float sum = blk_sum<256>(e0 + e1, sh);
  float inv = 1.f / sum;
  float a0 = e0*inv, a1 = e1*inv;
  row[tid] = a0; row[tid+256] = a1;
  float pr0 = posr[bi*HW_ + tid],        pr1 = posr[(B_+bi)*HW_ + tid];
  float pi0 = posi[bi*HW_ + tid],        pi1 = posi[(B_+bi)*HW_ + tid];
  float mr = blk_sum<256>(a0*pr0 + a1*pr1, sh);
  float mi = blk_sum<256>(a0*pi0 + a1*pi1, sh);
  if (!tid) { ws[OFF_MR + bi*512 + iq] = mr; ws[OFF_MI + bi*512 + iq] = mi; }
}

// ---- 11: t3 = A @ (mem * pos), split-K=2, partials ----
__global__ void __launch_bounds__(128) k_crossapply(float* ws, const float* posr, const float* posi) {
  int bx = blockIdx.x;               // 512 = kc(2)*bi(2)*qt(16)*dt(8)
  int dt = bx & 7, qt = (bx>>3)&15, bi = (bx>>7)&1, kc = bx>>8;
  const float* A  = ws + OFF_AC + (size_t)bi*262144;
  const float* Mr = ws + OFF_YSR; const float* Mi = ws + OFF_YSI;
  float* Pr = ws + (kc ? OFF_TSR : OFF_T3R);
  float* Pi = ws + (kc ? OFF_TSI : OFF_T3I);
  __shared__ float As[32][33], Vrs[32][68], Vis[32][68];
  int tid = threadIdx.x, ty = tid>>4, tx = tid&15;
  int ty4 = ty*4, tx4 = tx*4;
  float ar[4][4] = {}, ai[4][4] = {};
  for (int c = 0; c < 8; ++c) {
    int kb = kc*256 + c*32;
    #pragma unroll
    for (int it = 0; it < 8; ++it) {
      int i = it*128 + tid; int row = i>>5, col = i&31;
      As[row][col] = A[(size_t)(qt*32+row)*512 + kb+col];
    }
    #pragma unroll
    for (int it = 0; it < 16; ++it) {
      int i = it*128 + tid; int row = i>>6, col = i&63;
      int l = kb + row; int nil = l>>8, pl = l&255;
      float pvr = posr[(nil*B_ + bi)*HW_ + pl];
      float pvi = posi[(nil*B_ + bi)*HW_ + pl];
      size_t vb = (size_t)(l*B_ + bi)*D_ + dt*64+col;
      Vrs[row][col] = Mr[vb] * pvr;
      Vis[row][col] = Mi[vb] * pvi;
    }
    __syncthreads();
    #pragma unroll
    for (int kk = 0; kk < 32; ++kk) {
      float4 vr = *(const float4*)&Vrs[kk][tx4];
      float4 vi = *(const float4*)&Vis[kk][tx4];
      #pragma unroll
      for (int i = 0; i < 4; ++i) {
        float a = As[ty4+i][kk];
        ar[i][0] += a*vr.x; ar[i][1] += a*vr.y; ar[i][2] += a*vr.z; ar[i][3] += a*vr.w;
        ai[i][0] += a*vi.x; ai[i][1] += a*vi.y; ai[i][2] += a*vi.z; ai[i][3] += a*vi.w;
      }
    }
    __syncthreads();
  }
  #pragma unroll
  for (int i = 0; i < 4; ++i) {
    size_t o = (size_t)((qt*32+ty4+i)*B_ + bi)*D_ + dt*64 + tx4;
    #pragma unroll
    for (int j = 0; j < 4; ++j) { Pr[o+j] = ar[i][j]; Pi[o+j] = ai[i][j]; }
  }
}

// ---- 12: ss for (x*m)^2 (r,i) and (x+t3)^2 (r,i); t3 = sum of 2 partials ----
__global__ void k_reducey24(float* ws) {
  int qy = blockIdx.y;
  int g = blockIdx.x / NBLK_, blk = blockIdx.x % NBLK_;
  int ni = g>>1, bi = g&1;
  const float* X   = ws + ((qy==0 || qy==2) ? OFF_YTR : OFF_YTI);
  const float* T3a = ws + ((qy==2) ? OFF_T3R : OFF_T3I);
  const float* T3b = ws + ((qy==2) ? OFF_TSR : OFF_TSI);
  const float* M   = ws + ((qy==0) ? OFF_MR : OFF_MI);
  int tid = threadIdx.x;
  float acc = 0.f;
  for (int p = blk; p < HW_; p += NBLK_) {
    int l = ni*HW_ + p;
    size_t rb = (size_t)(l*B_ + bi)*D_;
    if (qy < 2) {
      float m = M[bi*512 + l];
      for (int d = tid; d < D_; d += 256) { float v = X[rb+d]*m; acc += v*v; }
    } else {
      for (int d = tid; d < D_; d += 256) { float v = X[rb+d] + T3a[rb+d] + T3b[rb+d]; acc += v*v; }
    }
  }
  __shared__ float sh[256];
  float s = blk_sum<256>(acc, sh);
  if (!tid) ws[OFF_P2 + (size_t)(qy*G_ + g)*NBLK_ + blk] = s;
}

// ---- 14: z = a2*(x*m) + a4*(x+t3) (into T3a) + ss(z) partials ----
__global__ void k_combine(float* ws, const float* scales2) {
  int y = blockIdx.y;                // 0=r, 1=i
  int g = blockIdx.x / NBLK_, blk = blockIdx.x % NBLK_;
  int ni = g>>1, bi = g&1;
  const float* X   = ws + (y ? OFF_YTI : OFF_YTR);
  float* T3a       = ws + (y ? OFF_T3I : OFF_T3R);
  const float* T3b = ws + (y ? OFF_TSI : OFF_TSR);
  const float* M   = ws + (y ? OFF_MI : OFF_MR);
  float a2 = scales2[y*G_ + g], a4 = scales2[(2+y)*G_ + g];
  int tid = threadIdx.x;
  float acc = 0.f;
  for (int p = blk; p < HW_; p += NBLK_) {
    int l = ni*HW_ + p;
    float m = M[bi*512 + l];
    size_t rb = (size_t)(l*B_ + bi)*D_;
    for (int d = tid; d < D_; d += 256) {
      float x = X[rb+d];
      float z = a2*(x*m) + a4*(x + T3a[rb+d] + T3b[rb+d]);
      T3a[rb+d] = z;
      acc += z*z;
    }
  }
  __shared__ float sh[256];
  float s = blk_sum<256>(acc, sh);
  if (!tid) ws[OFF_P3 + (size_t)(y*G_ + g)*NBLK_ + blk] = s;
}

// ---- 16: out = z*scale; feat = transpose(out) ----
__global__ void k_final(float* ws, const float* scalesZ, float* out) {
  int y = blockIdx.y;                // 0=r, 1=i
  int bx = blockIdx.x;               // 128 = nb(4)*dt(8)*pt(4)
  int pt = bx & 3, dt = (bx>>2)&7, nb = bx>>5;
  int ni = nb>>1, bi = nb&1;
  const float* Z = ws + (y ? OFF_T3I : OFF_T3R);
  float s = scalesZ[y*G_ + nb];
  float* o1 = out + (size_t)y*524288;        // out_r / out_i
  float* o2 = out + (size_t)(2+y)*524288;    // feat_r / feat_i
  __shared__ float tile[64][65];
  int tid = threadIdx.x;
  int p0 = pt*64, d0 = dt*64;
  #pragma unroll
  for (int it = 0; it < 16; ++it) {
    int i = it*256 + tid; int row = i>>6, col = i&63;   // row=p_local, col=d_local
    size_t idx = (size_t)((ni*HW_ + p0+row)*B_ + bi)*D_ + d0+col;
    float v = Z[idx] * s;
    o1[idx] = v;
    tile[row][col] = v;
  }
  __syncthreads();
  #pragma unroll
  for (int it = 0; it < 16; ++it) {
    int i = it*256 + tid; int row = i>>6, col = i&63;   // row=d_local, col=p_local
    o2[(size_t)(nb*D_ + d0+row)*HW_ + p0+col] = tile[col][row];
  }
}

extern "C" void kernel_launch(void* const* d_in, const int* in_sizes, int n_in,
                              void* d_out, int out_size, void* d_ws, size_t ws_size,
                              hipStream_t stream) {
  const float* srcR = (const float*)d_in[0];
  const float* srcI = (const float*)d_in[1];
  const float* tgtR = (const float*)d_in[2];
  const float* tgtI = (const float*)d_in[3];
  const float* esr  = (const float*)d_in[4];
  const float* esi  = (const float*)d_in[5];
  const float* etr  = (const float*)d_in[6];
  const float* eti  = (const float*)d_in[7];
  const float* posR = (const float*)d_in[8];
  const float* posI = (const float*)d_in[9];
  const float* WKrel   = (const float*)d_in[10];
  const float* WKcross = (const float*)d_in[11];
  float* ws  = (float*)d_ws;
  float* out = (float*)d_out;

  k_transpose <<<dim3(128,4), 256, 0, stream>>>(srcR, srcI, tgtR, tgtI, ws);
  k_qrel      <<<2048, 128, 0, stream>>>(ws, WKrel);
  k_gram      <<<256, 128, 0, stream>>>(ws);
  k_selfattn  <<<2048, 256, 0, stream>>>(ws, esr, esi, etr, eti);
  k_selfapply <<<512, 128, 0, stream>>>(ws);
  k_reduce4   <<<dim3(G_*NBLK_,4), 256, 0, stream>>>(ws);
  k_finalize  <<<1, 64, 0, stream>>>(ws + OFF_P1, ws + OFF_S1, 16);
  k_applyscale<<<dim3(512,4), 256, 0, stream>>>(ws, ws + OFF_S1);
  k_crossproj <<<2048, 128, 0, stream>>>(ws, WKcross);
  k_crossscore<<<256, 128, 0, stream>>>(ws);
  k_softmaxrow<<<1024, 256, 0, stream>>>(ws, posR, posI);
  k_crossapply<<<512, 128, 0, stream>>>(ws, posR, posI);
  k_reducey24 <<<dim3(G_*NBLK_,4), 256, 0, stream>>>(ws);
  k_finalize  <<<1, 64, 0, stream>>>(ws + OFF_P2, ws + OFF_S2, 16);
  k_combine   <<<dim3(G_*NBLK_,2), 256, 0, stream>>>(ws, ws + OFF_S2);
  k_finalize  <<<1, 64, 0, stream>>>(ws + OFF_P3, ws + OFF_SZ, 8);
  k_final     <<<dim3(128,2), 256, 0, stream>>>(ws, ws + OFF_SZ, out);
}